// Round 7
// baseline (345.736 us; speedup 1.0000x reference)
//
#include <hip/hip_runtime.h>

typedef _Float16 f16;
typedef f16 f16x8 __attribute__((ext_vector_type(8)));
typedef f16 f16x4 __attribute__((ext_vector_type(4)));
typedef f16 hf2 __attribute__((ext_vector_type(2)));
typedef float f32x4 __attribute__((ext_vector_type(4)));
typedef unsigned int u32;
typedef unsigned short u16;

#define QL 1024
#define KL 1024
#define DKD 64
#define NH 8
#define LNEPS 1e-5f

__device__ __forceinline__ hf2 pkrtz(float a, float b) {
  return __builtin_bit_cast(hf2, __builtin_amdgcn_cvt_pkrtz(a, b));
}
__device__ __forceinline__ hf2 bch(u32 v) { return __builtin_bit_cast(hf2, v); }

// ---- prep: K,Q f32 -> f16 planes (+ pack hA/lnw/lnb as f16-pair u32) ----
__global__ __launch_bounds__(256) void prep_qk(const float* __restrict__ K,
    const float* __restrict__ Q, f16* __restrict__ kf, f16* __restrict__ qf,
    const float* __restrict__ hA, const float* __restrict__ lnw,
    const float* __restrict__ lnb, u32* __restrict__ prm) {
  const int bid = blockIdx.x;
  if (bid == 0 && threadIdx.x < 80) {
    int t = threadIdx.x;
    float v = t < 64 ? hA[t] : (t < 72 ? lnw[t - 64] : lnb[t - 72]);
    u16 hb = __builtin_bit_cast(u16, (f16)v);
    prm[t] = (u32)hb * 0x10001u;
  }
  const bool isQ = bid >= 4096;
  const float* src = isQ ? Q : K;
  f16* dst = isQ ? qf : kf;
  const float scale = isQ ? 0.125f : 1.0f;
  int i = ((bid & 4095) * 256 + threadIdx.x) * 4;
  float4 v = *reinterpret_cast<const float4*>(src + i);
  f16x4 o;
  o[0] = (f16)(v.x * scale); o[1] = (f16)(v.y * scale);
  o[2] = (f16)(v.z * scale); o[3] = (f16)(v.w * scale);
  *reinterpret_cast<f16x4*>(dst + i) = o;
}

// ---- prep: V[bh][k][d] f32 -> vt[bh][d][k] f16 (transpose) ----
__global__ __launch_bounds__(256) void prep_vt(const float* __restrict__ V, f16* __restrict__ vt) {
  __shared__ float t[32][33];
  const int bh = blockIdx.z, k0 = blockIdx.x * 32, d0 = blockIdx.y * 32;
  const float* src = V + ((size_t)bh * KL + k0) * DKD + d0;
#pragma unroll
  for (int j = 0; j < 4; ++j) {
    int kk = threadIdx.y * 4 + j;
    t[kk][threadIdx.x] = src[kk * DKD + threadIdx.x];
  }
  __syncthreads();
  f16* dst = vt + ((size_t)bh * DKD + d0) * KL + k0;
#pragma unroll
  for (int j = 0; j < 4; ++j) {
    int dd = threadIdx.y * 4 + j;
    dst[dd * KL + threadIdx.x] = (f16)t[threadIdx.x][dd];
  }
}

// ---- stats, split-k x4: prs4[kq][bh][q] = sum over k-quarter of exp(s) ----
// block = (b,h,kq,q64); 4 waves share one 32KB K-quarter slice (L1 reuse).
__global__ __launch_bounds__(256) void stats4(const f16* __restrict__ qf,
    const f16* __restrict__ kf, float* __restrict__ prs4) {
  const int tid = threadIdx.x, lane = tid & 63, w = tid >> 6;
  const int m = lane & 15, g = lane >> 4;
  int id = blockIdx.x;
  const int b = id & 7; id >>= 3;
  const int h = id & 7; id >>= 3;
  const int kq = id & 3; const int q64 = id >> 2;
  const int bh = b * 8 + h;
  const int q0 = q64 * 64 + w * 16;

  const f16* qp = qf + ((size_t)bh * QL + q0 + m) * DKD + g * 8;
  f16x8 qv0 = *reinterpret_cast<const f16x8*>(qp);
  f16x8 qv1 = *reinterpret_cast<const f16x8*>(qp + 32);

  float part[4] = {0.f, 0.f, 0.f, 0.f};
#pragma unroll 2
  for (int kt = 0; kt < 16; ++kt) {
    const f16* kb = kf + ((size_t)bh * KL + kq * 256 + kt * 16 + m) * DKD + g * 8;
    f16x8 k0f = *reinterpret_cast<const f16x8*>(kb);
    f16x8 k1f = *reinterpret_cast<const f16x8*>(kb + 32);
    f32x4 acc = {0.f, 0.f, 0.f, 0.f};
    acc = __builtin_amdgcn_mfma_f32_16x16x32_f16(qv0, k0f, acc, 0, 0, 0);
    acc = __builtin_amdgcn_mfma_f32_16x16x32_f16(qv1, k1f, acc, 0, 0, 0);
#pragma unroll
    for (int ri = 0; ri < 4; ++ri) part[ri] += __expf(acc[ri]);
  }
#pragma unroll
  for (int ri = 0; ri < 4; ++ri) {
    float v = part[ri];
    v += __shfl_xor(v, 1); v += __shfl_xor(v, 2);
    v += __shfl_xor(v, 4); v += __shfl_xor(v, 8);
    part[ri] = v;
  }
  if (m == 0) {
#pragma unroll
    for (int ri = 0; ri < 4; ++ri)
      prs4[((size_t)kq * 64 + bh) * QL + q0 + g * 4 + ri] = part[ri];
  }
}

// ---- lrs[bh][q] = log(sum of 4 partials) ----
__global__ __launch_bounds__(256) void stats_red(const float* __restrict__ prs4,
                                                 float* __restrict__ lrs) {
  int i = (blockIdx.x * 256 + threadIdx.x) * 4;
  float4 a = *reinterpret_cast<const float4*>(prs4 + i);
  float4 c = *reinterpret_cast<const float4*>(prs4 + 65536 + i);
  float4 d = *reinterpret_cast<const float4*>(prs4 + 131072 + i);
  float4 e = *reinterpret_cast<const float4*>(prs4 + 196608 + i);
  float4 o;
  o.x = __logf(a.x + c.x + d.x + e.x);
  o.y = __logf(a.y + c.y + d.y + e.y);
  o.z = __logf(a.z + c.z + d.z + e.z);
  o.w = __logf(a.w + c.w + d.w + e.w);
  *reinterpret_cast<float4*>(lrs + i) = o;
}

// ---- mix: S -> p=exp(s-lrs) -> packed-f16 head-mix -> LN -> att_map + y(global) ----
// One q-quarter per launch. block=(b,q64t,k32); 4 waves = 4 q16 sub-tiles
// sharing the K slice (L1). No LDS, no barriers, waves fully independent.
__global__ __launch_bounds__(256) void mix_kernel(const f16* __restrict__ qf,
    const f16* __restrict__ kf, const float* __restrict__ lrs_g,
    const u32* __restrict__ prm, f16* __restrict__ yq, float* __restrict__ att_map,
    int qs) {
  const int tid = threadIdx.x, lane = tid & 63, w = tid >> 6;
  const int m = lane & 15, g = lane >> 4;
  int id = blockIdx.x;
  const int b = id & 7; id >>= 3;
  const int k32 = id & 31; const int q64t = id >> 5;   // 8*32*4 = 1024 blocks
  const int q0 = qs * 256 + q64t * 64 + w * 16;
  const int qrow = q0 + g * 4;
  const int qLrow = q64t * 64 + w * 16 + g * 4;        // local row in quarter

  // uniform packed params (SGPR-resident; verified pattern rounds 1-6)
  u32 prmL[80];
#pragma unroll
  for (int j = 0; j < 80; ++j) prmL[j] = prm[j];

  float lrs[NH][4];
#pragma unroll
  for (int h = 0; h < NH; ++h) {
    f32x4 l4 = *reinterpret_cast<const f32x4*>(lrs_g + (((size_t)(b * 8 + h)) << 10) + qrow);
#pragma unroll
    for (int ri = 0; ri < 4; ++ri) lrs[h][ri] = l4[ri];
  }

  const hf2 c125 = {(f16)0.125f, (f16)0.125f};

  for (int kt = 0; kt < 2; ++kt) {
    const int k0 = k32 * 32 + kt * 16;
    // S phase: 8 heads, 16q x 16k; p packed as f16 q-pairs
    hf2 pP[NH][2];
#pragma unroll
    for (int h = 0; h < NH; ++h) {
      const f16* qp = qf + ((((size_t)(b * 8 + h)) << 10) + q0 + m) * DKD + g * 8;
      const f16* kp = kf + ((((size_t)(b * 8 + h)) << 10) + k0 + m) * DKD + g * 8;
      f32x4 acc = {0.f, 0.f, 0.f, 0.f};
      acc = __builtin_amdgcn_mfma_f32_16x16x32_f16(
          *reinterpret_cast<const f16x8*>(qp), *reinterpret_cast<const f16x8*>(kp), acc, 0, 0, 0);
      acc = __builtin_amdgcn_mfma_f32_16x16x32_f16(
          *reinterpret_cast<const f16x8*>(qp + 32), *reinterpret_cast<const f16x8*>(kp + 32), acc, 0, 0, 0);
      pP[h][0] = pkrtz(__expf(acc[0] - lrs[h][0]), __expf(acc[1] - lrs[h][1]));
      pP[h][1] = pkrtz(__expf(acc[2] - lrs[h][2]), __expf(acc[3] - lrs[h][3]));
    }
    // head-mix in packed f16 (2 q-rows per op)
    hf2 mx[NH][2];
#pragma unroll
    for (int hh = 0; hh < NH; ++hh)
#pragma unroll
      for (int pp = 0; pp < 2; ++pp) {
        hf2 acc = pP[0][pp] * bch(prmL[hh]);
#pragma unroll
        for (int j = 1; j < 8; ++j) acc += pP[j][pp] * bch(prmL[j * 8 + hh]);
        mx[hh][pp] = acc;
      }
    // LN over heads (packed)
    hf2 mu[2], var[2];
#pragma unroll
    for (int pp = 0; pp < 2; ++pp) {
      hf2 s = mx[0][pp];
#pragma unroll
      for (int hh = 1; hh < NH; ++hh) s += mx[hh][pp];
      mu[pp] = s * c125;
    }
#pragma unroll
    for (int pp = 0; pp < 2; ++pp) {
      hf2 v = {};
#pragma unroll
      for (int hh = 0; hh < NH; ++hh) {
        mx[hh][pp] -= mu[pp];
        v += mx[hh][pp] * mx[hh][pp];
      }
      var[pp] = v * c125;
    }
    float r0 = rsqrtf((float)var[0][0] + LNEPS);
    float r1 = rsqrtf((float)var[0][1] + LNEPS);
    float r2 = rsqrtf((float)var[1][0] + LNEPS);
    float r3 = rsqrtf((float)var[1][1] + LNEPS);
    hf2 rsv[2] = {pkrtz(r0, r1), pkrtz(r2, r3)};
    hf2 am[2] = {{}, {}};
#pragma unroll
    for (int hh = 0; hh < NH; ++hh) {
      f16* yb = yq + ((((size_t)(b * 8 + hh)) << 8) + qLrow) * KL + k0 + m;
#pragma unroll
      for (int pp = 0; pp < 2; ++pp) {
        hf2 t = mx[hh][pp] * rsv[pp];
        hf2 y = t * bch(prmL[64 + hh]) + bch(prmL[72 + hh]);
        am[pp] += y;
        yb[(2 * pp) * KL] = y[0];
        yb[(2 * pp + 1) * KL] = y[1];
      }
    }
    float* ab = att_map + ((((size_t)b) << 10) + qrow) * KL + k0 + m;
    ab[0]        = (float)am[0][0] * 0.125f;
    ab[KL]       = (float)am[0][1] * 0.125f;
    ab[2 * KL]   = (float)am[1][0] * 0.125f;
    ab[3 * KL]   = (float)am[1][1] * 0.125f;
  }
}

// ---- pv: out[bh][q][d] = y[bh][q][:] . V[bh][:][d]  (streaming GEMM) ----
// block=(b,h,q64t,dq); wave = one 16q x 16d tile over full k. ~35 VGPR, no sync.
__global__ __launch_bounds__(256) void pv_kernel(const f16* __restrict__ yq,
    const f16* __restrict__ vt, float* __restrict__ outp, int qs) {
  const int tid = threadIdx.x, lane = tid & 63, w = tid >> 6;
  const int m = lane & 15, g = lane >> 4;
  int id = blockIdx.x;
  const int b = id & 7; id >>= 3;
  const int h = id & 7; id >>= 3;
  const int q64t = id & 3; const int dq = id >> 2;   // 8*8*4*4 = 1024 blocks
  const int q0L = q64t * 64 + w * 16;
  const int bh = b * 8 + h;

  const f16* ab = yq + ((((size_t)bh) << 8) + q0L + m) * KL + g * 8;
  const f16* bb = vt + ((size_t)bh * DKD + dq * 16 + m) * KL + g * 8;
  f32x4 acc = {0.f, 0.f, 0.f, 0.f};
#pragma unroll 4
  for (int kk = 0; kk < 32; ++kk) {
    f16x8 af = *reinterpret_cast<const f16x8*>(ab + kk * 32);
    f16x8 bf = *reinterpret_cast<const f16x8*>(bb + kk * 32);
    acc = __builtin_amdgcn_mfma_f32_16x16x32_f16(af, bf, acc, 0, 0, 0);
  }
  const int q = qs * 256 + q0L + g * 4;
  float* ob = outp + ((((size_t)bh) << 10) + q) * DKD + dq * 16 + m;
#pragma unroll
  for (int ri = 0; ri < 4; ++ri) ob[ri * DKD] = acc[ri];
}

extern "C" void kernel_launch(void* const* d_in, const int* in_sizes, int n_in,
                              void* d_out, int out_size, void* d_ws, size_t ws_size,
                              hipStream_t stream) {
  const float* Qm  = (const float*)d_in[0];
  const float* Km  = (const float*)d_in[1];
  const float* Vm  = (const float*)d_in[2];
  const float* hA  = (const float*)d_in[3];
  const float* lnw = (const float*)d_in[4];
  const float* lnb = (const float*)d_in[5];
  float* outp = (float*)d_out;
  float* att_map = outp + (size_t)64 * QL * DKD;

  char* ws = (char*)d_ws;
  f16* kfp    = (f16*)ws;                              // 8 MB
  f16* vtp    = (f16*)(ws + (size_t)8388608);          // 8 MB
  f16* qfp    = (f16*)(ws + (size_t)16777216);         // 8 MB
  float* prs4 = (float*)(ws + (size_t)25165824);       // 1 MB
  float* lrs  = (float*)(ws + (size_t)26214400);       // 1 MB
  u32* prm    = (u32*)(ws + (size_t)27262976);         // 320 B
  f16* yqb    = (f16*)(ws + (size_t)28311552);         // 33.5 MB (q-quarter y)

  prep_qk<<<8192, 256, 0, stream>>>(Km, Qm, kfp, qfp, hA, lnw, lnb, prm);
  prep_vt<<<dim3(32, 2, 64), dim3(32, 8), 0, stream>>>(Vm, vtp);
  stats4<<<4096, 256, 0, stream>>>(qfp, kfp, prs4);
  stats_red<<<256, 256, 0, stream>>>(prs4, lrs);
  for (int qs = 0; qs < 4; ++qs) {
    mix_kernel<<<1024, 256, 0, stream>>>(qfp, kfp, lrs, prm, yqb, att_map, qs);
    pv_kernel<<<1024, 256, 0, stream>>>(yqb, vtp, outp, qs);
  }
}

// Round 8
// 233.164 us; speedup vs baseline: 1.4828x; 1.4828x over previous
//
#include <hip/hip_runtime.h>

typedef _Float16 f16;
typedef f16 f16x8 __attribute__((ext_vector_type(8)));
typedef f16 f16x4 __attribute__((ext_vector_type(4)));
typedef f16 hf2 __attribute__((ext_vector_type(2)));
typedef float f32x4 __attribute__((ext_vector_type(4)));
typedef unsigned int u32;
typedef unsigned short u16;

#define QL 1024
#define KL 1024
#define DKD 64
#define NH 8
#define LNEPS 1e-5f

__device__ __forceinline__ hf2 pkrtz(float a, float b) {
  return __builtin_bit_cast(hf2, __builtin_amdgcn_cvt_pkrtz(a, b));
}
__device__ __forceinline__ hf2 bch(u32 v) { return __builtin_bit_cast(hf2, v); }

// ---- prep: K,Q f32 -> f16 planes (+ pack hA/lnw/lnb as f16-pair u32) ----
__global__ __launch_bounds__(256) void prep_qk(const float* __restrict__ K,
    const float* __restrict__ Q, f16* __restrict__ kf, f16* __restrict__ qf,
    const float* __restrict__ hA, const float* __restrict__ lnw,
    const float* __restrict__ lnb, u32* __restrict__ prm) {
  const int bid = blockIdx.x;
  if (bid == 0 && threadIdx.x < 80) {
    int t = threadIdx.x;
    float v = t < 64 ? hA[t] : (t < 72 ? lnw[t - 64] : lnb[t - 72]);
    u16 hb = __builtin_bit_cast(u16, (f16)v);
    prm[t] = (u32)hb * 0x10001u;
  }
  const bool isQ = bid >= 4096;
  const float* src = isQ ? Q : K;
  f16* dst = isQ ? qf : kf;
  const float scale = isQ ? 0.125f : 1.0f;
  int i = ((bid & 4095) * 256 + threadIdx.x) * 4;
  float4 v = *reinterpret_cast<const float4*>(src + i);
  f16x4 o;
  o[0] = (f16)(v.x * scale); o[1] = (f16)(v.y * scale);
  o[2] = (f16)(v.z * scale); o[3] = (f16)(v.w * scale);
  *reinterpret_cast<f16x4*>(dst + i) = o;
}

// ---- prep: V[bh][k][d] f32 -> vt[bh][d][k] f16 (transpose) ----
__global__ __launch_bounds__(256) void prep_vt(const float* __restrict__ V, f16* __restrict__ vt) {
  __shared__ float t[32][33];
  const int bh = blockIdx.z, k0 = blockIdx.x * 32, d0 = blockIdx.y * 32;
  const float* src = V + ((size_t)bh * KL + k0) * DKD + d0;
#pragma unroll
  for (int j = 0; j < 4; ++j) {
    int kk = threadIdx.y * 4 + j;
    t[kk][threadIdx.x] = src[kk * DKD + threadIdx.x];
  }
  __syncthreads();
  f16* dst = vt + ((size_t)bh * DKD + d0) * KL + k0;
#pragma unroll
  for (int j = 0; j < 4; ++j) {
    int dd = threadIdx.y * 4 + j;
    dst[dd * KL + threadIdx.x] = (f16)t[threadIdx.x][dd];
  }
}

// ---- stats: K-quarter staged in LDS (swizzled), 4 waves compute from LDS ----
__global__ __launch_bounds__(256) void stats_lds(const f16* __restrict__ qf,
    const f16* __restrict__ kf, float* __restrict__ prs4) {
  __shared__ __align__(16) char kb[32768];
  const int tid = threadIdx.x, lane = tid & 63, w = tid >> 6;
  const int m = lane & 15, g = lane >> 4;
  int id = blockIdx.x;
  const int b = id & 7, h = (id >> 3) & 7, kq = (id >> 6) & 3, q64 = (id >> 8) & 15;
  const int bh = b * 8 + h;

  // stage 256k x 64d (32 KB), 16B-chunk col XOR-swizzled by (row&7)
  const f16* sbase = kf + (((size_t)bh << 10) + kq * 256) * DKD;
#pragma unroll
  for (int j = 0; j < 8; ++j) {
    int idx = j * 256 + tid;
    int r = idx >> 3, c = idx & 7;
    f16x8 v = *reinterpret_cast<const f16x8*>(sbase + r * DKD + c * 8);
    *reinterpret_cast<f16x8*>(kb + r * 128 + ((c ^ (r & 7)) << 4)) = v;
  }
  const int q0 = q64 * 64 + w * 16;
  const f16* qp = qf + (((size_t)bh << 10) + q0 + m) * DKD + g * 8;
  f16x8 qv0 = *reinterpret_cast<const f16x8*>(qp);
  f16x8 qv1 = *reinterpret_cast<const f16x8*>(qp + 32);
  __syncthreads();

  float part[4] = {0.f, 0.f, 0.f, 0.f};
#pragma unroll 4
  for (int kt = 0; kt < 16; ++kt) {
    const int row = kt * 16 + m;
    f16x8 k0f = *reinterpret_cast<const f16x8*>(kb + row * 128 + ((g ^ (m & 7)) << 4));
    f16x8 k1f = *reinterpret_cast<const f16x8*>(kb + row * 128 + (((g + 4) ^ (m & 7)) << 4));
    f32x4 acc = {0.f, 0.f, 0.f, 0.f};
    acc = __builtin_amdgcn_mfma_f32_16x16x32_f16(qv0, k0f, acc, 0, 0, 0);
    acc = __builtin_amdgcn_mfma_f32_16x16x32_f16(qv1, k1f, acc, 0, 0, 0);
#pragma unroll
    for (int ri = 0; ri < 4; ++ri) part[ri] += __expf(acc[ri]);
  }
#pragma unroll
  for (int ri = 0; ri < 4; ++ri) {
    float v = part[ri];
    v += __shfl_xor(v, 1); v += __shfl_xor(v, 2);
    v += __shfl_xor(v, 4); v += __shfl_xor(v, 8);
    part[ri] = v;
  }
  if (m == 0) {
#pragma unroll
    for (int ri = 0; ri < 4; ++ri)
      prs4[((size_t)kq * 64 + bh) * QL + q0 + g * 4 + ri] = part[ri];
  }
}

// ---- lrs[bh][q] = log(sum of 4 partials) ----
__global__ __launch_bounds__(256) void stats_red(const float* __restrict__ prs4,
                                                 float* __restrict__ lrs) {
  int i = (blockIdx.x * 256 + threadIdx.x) * 4;
  float4 a = *reinterpret_cast<const float4*>(prs4 + i);
  float4 c = *reinterpret_cast<const float4*>(prs4 + 65536 + i);
  float4 d = *reinterpret_cast<const float4*>(prs4 + 131072 + i);
  float4 e = *reinterpret_cast<const float4*>(prs4 + 196608 + i);
  float4 o;
  o.x = __logf(a.x + c.x + d.x + e.x);
  o.y = __logf(a.y + c.y + d.y + e.y);
  o.z = __logf(a.z + c.z + d.z + e.z);
  o.w = __logf(a.w + c.w + d.w + e.w);
  *reinterpret_cast<float4*>(lrs + i) = o;
}

// ---- mix: K-tile(8h x 32k) in LDS; S->p->mix->LN; att+y via LDS-coalesced writes ----
// smem: [0,32768) K tile (reused as y bounce), [32768,40960) att f32 tile.
__global__ __launch_bounds__(256) void mix_lds(const f16* __restrict__ qf,
    const f16* __restrict__ kf, const float* __restrict__ lrs_g,
    const u32* __restrict__ prm, f16* __restrict__ yq, float* __restrict__ att_map,
    int qs) {
  __shared__ __align__(16) char smem[40960];
  const int tid = threadIdx.x, lane = tid & 63, w = tid >> 6;
  const int m = lane & 15, g = lane >> 4;
  int id = blockIdx.x;
  const int b = id & 7, k32 = (id >> 3) & 31, qsub = (id >> 8) & 3;
  const int q0 = qsub * 64 + w * 16;          // quarter-local wave q base
  const int qg = qs * 256 + q0;               // global q base
  const int k0b = k32 * 32;

  u32 prmL[80];
#pragma unroll
  for (int j = 0; j < 80; ++j) prmL[j] = prm[j];

  // stage K tile rows r = h*32+kr, swizzled
#pragma unroll
  for (int j = 0; j < 8; ++j) {
    int idx = j * 256 + tid;
    int r = idx >> 3, c = idx & 7;
    int h = r >> 5, kr = r & 31;
    const f16* src = kf + ((((size_t)(b * 8 + h)) << 10) + k0b + kr) * DKD + c * 8;
    f16x8 v = *reinterpret_cast<const f16x8*>(src);
    *reinterpret_cast<f16x8*>(smem + r * 128 + ((c ^ (r & 7)) << 4)) = v;
  }
  __syncthreads();

  const hf2 c125 = {(f16)0.125f, (f16)0.125f};
  hf2 yv[2][NH][2];   // [kt][h][q-pair]

#pragma unroll
  for (int kt = 0; kt < 2; ++kt) {
    hf2 pP[NH][2];
#pragma unroll
    for (int h = 0; h < NH; ++h) {
      const f16* qp = qf + ((((size_t)(b * 8 + h)) << 10) + qg + m) * DKD + g * 8;
      f16x8 q0f = *reinterpret_cast<const f16x8*>(qp);
      f16x8 q1f = *reinterpret_cast<const f16x8*>(qp + 32);
      const int row = h * 32 + kt * 16 + m;
      f16x8 ka = *reinterpret_cast<const f16x8*>(smem + row * 128 + ((g ^ (m & 7)) << 4));
      f16x8 kc = *reinterpret_cast<const f16x8*>(smem + row * 128 + (((g + 4) ^ (m & 7)) << 4));
      f32x4 acc = {0.f, 0.f, 0.f, 0.f};
      acc = __builtin_amdgcn_mfma_f32_16x16x32_f16(q0f, ka, acc, 0, 0, 0);
      acc = __builtin_amdgcn_mfma_f32_16x16x32_f16(q1f, kc, acc, 0, 0, 0);
      f32x4 l4 = *reinterpret_cast<const f32x4*>(
          lrs_g + ((((size_t)(b * 8 + h)) << 10) + qg + g * 4));
      pP[h][0] = pkrtz(__expf(acc[0] - l4[0]), __expf(acc[1] - l4[1]));
      pP[h][1] = pkrtz(__expf(acc[2] - l4[2]), __expf(acc[3] - l4[3]));
    }
    // packed head-mix + LN
    hf2 mx[NH][2];
#pragma unroll
    for (int hh = 0; hh < NH; ++hh)
#pragma unroll
      for (int pp = 0; pp < 2; ++pp) {
        hf2 acc = pP[0][pp] * bch(prmL[hh]);
#pragma unroll
        for (int j = 1; j < 8; ++j) acc += pP[j][pp] * bch(prmL[j * 8 + hh]);
        mx[hh][pp] = acc;
      }
    hf2 mu[2], var[2];
#pragma unroll
    for (int pp = 0; pp < 2; ++pp) {
      hf2 s = mx[0][pp];
#pragma unroll
      for (int hh = 1; hh < NH; ++hh) s += mx[hh][pp];
      mu[pp] = s * c125;
    }
#pragma unroll
    for (int pp = 0; pp < 2; ++pp) {
      hf2 v = {};
#pragma unroll
      for (int hh = 0; hh < NH; ++hh) {
        mx[hh][pp] -= mu[pp];
        v += mx[hh][pp] * mx[hh][pp];
      }
      var[pp] = v * c125;
    }
    hf2 rsv[2] = {pkrtz(rsqrtf((float)var[0][0] + LNEPS), rsqrtf((float)var[0][1] + LNEPS)),
                  pkrtz(rsqrtf((float)var[1][0] + LNEPS), rsqrtf((float)var[1][1] + LNEPS))};
    hf2 am[2] = {{}, {}};
#pragma unroll
    for (int hh = 0; hh < NH; ++hh)
#pragma unroll
      for (int pp = 0; pp < 2; ++pp) {
        hf2 y = mx[hh][pp] * rsv[pp] * bch(prmL[64 + hh]) + bch(prmL[72 + hh]);
        am[pp] += y;
        yv[kt][hh][pp] = y;
      }
    // att tile -> LDS (f32 region), coalesced write-out later
    const int kcol = kt * 16 + m;
#pragma unroll
    for (int pp = 0; pp < 2; ++pp) {
      int qrow0 = w * 16 + g * 4 + pp * 2;
      *reinterpret_cast<float*>(smem + 32768 + (qrow0 * 32 + kcol) * 4) = (float)am[pp][0] * 0.125f;
      *reinterpret_cast<float*>(smem + 32768 + ((qrow0 + 1) * 32 + kcol) * 4) = (float)am[pp][1] * 0.125f;
    }
  }
  __syncthreads();   // all K reads + att writes complete; K region now dead

  // y -> LDS bounce [8h][64q][32k] f16 into the dead K region
#pragma unroll
  for (int kt = 0; kt < 2; ++kt) {
    const int kcol = kt * 16 + m;
#pragma unroll
    for (int h = 0; h < NH; ++h)
#pragma unroll
      for (int pp = 0; pp < 2; ++pp) {
        int R = w * 16 + g * 4 + pp * 2;
        *reinterpret_cast<f16*>(smem + h * 4096 + R * 64 + kcol * 2) = yv[kt][h][pp][0];
        *reinterpret_cast<f16*>(smem + h * 4096 + (R + 1) * 64 + kcol * 2) = yv[kt][h][pp][1];
      }
  }
  __syncthreads();

  // coalesced write-out: y (8 x b128 per thread) + att (2 x b128 per thread)
#pragma unroll
  for (int j = 0; j < 8; ++j) {
    int idx = j * 256 + tid;
    int h = idx >> 8, R = (idx >> 2) & 63, kc = idx & 3;
    f16x8 v = *reinterpret_cast<const f16x8*>(smem + idx * 16);
    *reinterpret_cast<f16x8*>(
        yq + ((((size_t)(b * 8 + h)) * 256 + qsub * 64 + R) << 10) + k0b + kc * 8) = v;
  }
#pragma unroll
  for (int j = 0; j < 2; ++j) {
    int idx = j * 256 + tid;
    int q = idx >> 3, kc = idx & 7;
    f32x4 v = *reinterpret_cast<const f32x4*>(smem + 32768 + idx * 16);
    *reinterpret_cast<f32x4*>(
        att_map + ((((size_t)b << 10) + qs * 256 + qsub * 64 + q) << 10) + k0b + kc * 4) = v;
  }
}

// ---- pv: out[q16,d32] per wave, 2 MFMA chains share each y-load ----
__global__ __launch_bounds__(256) void pv_kernel(const f16* __restrict__ yq,
    const f16* __restrict__ vt, float* __restrict__ outp, int qs) {
  const int tid = threadIdx.x, lane = tid & 63, w = tid >> 6;
  const int m = lane & 15, g = lane >> 4;
  int id = blockIdx.x;
  const int b = id & 7, h = (id >> 3) & 7, q64 = (id >> 6) & 3, dh = (id >> 8) & 1;
  const int bh = b * 8 + h;
  const int qloc = q64 * 64 + w * 16;

  const f16* ab = yq + (((size_t)bh * 256) + qloc + m) * KL + g * 8;
  const f16* vb = vt + (((size_t)bh * DKD) + dh * 32 + m) * KL + g * 8;
  f32x4 a0 = {0.f, 0.f, 0.f, 0.f}, a1 = {0.f, 0.f, 0.f, 0.f};
#pragma unroll 4
  for (int t = 0; t < 32; ++t) {
    f16x8 yf = *reinterpret_cast<const f16x8*>(ab + t * 32);
    f16x8 v0 = *reinterpret_cast<const f16x8*>(vb + t * 32);
    f16x8 v1 = *reinterpret_cast<const f16x8*>(vb + 16 * KL + t * 32);
    a0 = __builtin_amdgcn_mfma_f32_16x16x32_f16(yf, v0, a0, 0, 0, 0);
    a1 = __builtin_amdgcn_mfma_f32_16x16x32_f16(yf, v1, a1, 0, 0, 0);
  }
  const int qglob = qs * 256 + qloc + g * 4;
  float* ob = outp + ((((size_t)bh) << 10) + qglob) * DKD + dh * 32 + m;
#pragma unroll
  for (int ri = 0; ri < 4; ++ri) {
    ob[ri * DKD] = a0[ri];
    ob[ri * DKD + 16] = a1[ri];
  }
}

extern "C" void kernel_launch(void* const* d_in, const int* in_sizes, int n_in,
                              void* d_out, int out_size, void* d_ws, size_t ws_size,
                              hipStream_t stream) {
  const float* Qm  = (const float*)d_in[0];
  const float* Km  = (const float*)d_in[1];
  const float* Vm  = (const float*)d_in[2];
  const float* hA  = (const float*)d_in[3];
  const float* lnw = (const float*)d_in[4];
  const float* lnb = (const float*)d_in[5];
  float* outp = (float*)d_out;
  float* att_map = outp + (size_t)64 * QL * DKD;

  char* ws = (char*)d_ws;
  f16* kfp    = (f16*)ws;                              // 8 MB
  f16* vtp    = (f16*)(ws + (size_t)8388608);          // 8 MB
  f16* qfp    = (f16*)(ws + (size_t)16777216);         // 8 MB
  float* prs4 = (float*)(ws + (size_t)25165824);       // 1 MB
  float* lrs  = (float*)(ws + (size_t)26214400);       // 1 MB
  u32* prm    = (u32*)(ws + (size_t)27262976);         // 320 B
  f16* yqb    = (f16*)(ws + (size_t)28311552);         // 33.5 MB (q-quarter y)

  prep_qk<<<8192, 256, 0, stream>>>(Km, Qm, kfp, qfp, hA, lnw, lnb, prm);
  prep_vt<<<dim3(32, 2, 64), dim3(32, 8), 0, stream>>>(Vm, vtp);
  stats_lds<<<4096, 256, 0, stream>>>(qfp, kfp, prs4);
  stats_red<<<256, 256, 0, stream>>>(prs4, lrs);
  for (int qs = 0; qs < 4; ++qs) {
    mix_lds<<<1024, 256, 0, stream>>>(qfp, kfp, lrs, prm, yqb, att_map, qs);
    pv_kernel<<<512, 256, 0, stream>>>(yqb, vtp, outp, qs);
  }
}

// Round 9
// 211.996 us; speedup vs baseline: 1.6309x; 1.0998x over previous
//
#include <hip/hip_runtime.h>

typedef _Float16 f16;
typedef f16 f16x8 __attribute__((ext_vector_type(8)));
typedef f16 f16x4 __attribute__((ext_vector_type(4)));
typedef f16 hf2 __attribute__((ext_vector_type(2)));
typedef float f32x4 __attribute__((ext_vector_type(4)));
typedef unsigned int u32;
typedef unsigned short u16;

#define QL 1024
#define KL 1024
#define DKD 64
#define NH 8
#define LNEPS 1e-5f

__device__ __forceinline__ hf2 pkrtz(float a, float b) {
  return __builtin_bit_cast(hf2, __builtin_amdgcn_cvt_pkrtz(a, b));
}
__device__ __forceinline__ hf2 bch(u32 v) { return __builtin_bit_cast(hf2, v); }

// ---- prep: K,Q f32 -> f16 planes (+ pack hA/lnw/lnb as f16-pair u32) ----
__global__ __launch_bounds__(256) void prep_qk(const float* __restrict__ K,
    const float* __restrict__ Q, f16* __restrict__ kf, f16* __restrict__ qf,
    const float* __restrict__ hA, const float* __restrict__ lnw,
    const float* __restrict__ lnb, u32* __restrict__ prm) {
  const int bid = blockIdx.x;
  if (bid == 0 && threadIdx.x < 80) {
    int t = threadIdx.x;
    float v = t < 64 ? hA[t] : (t < 72 ? lnw[t - 64] : lnb[t - 72]);
    u16 hb = __builtin_bit_cast(u16, (f16)v);
    prm[t] = (u32)hb * 0x10001u;
  }
  const bool isQ = bid >= 4096;
  const float* src = isQ ? Q : K;
  f16* dst = isQ ? qf : kf;
  const float scale = isQ ? 0.125f : 1.0f;
  int i = ((bid & 4095) * 256 + threadIdx.x) * 4;
  float4 v = *reinterpret_cast<const float4*>(src + i);
  f16x4 o;
  o[0] = (f16)(v.x * scale); o[1] = (f16)(v.y * scale);
  o[2] = (f16)(v.z * scale); o[3] = (f16)(v.w * scale);
  *reinterpret_cast<f16x4*>(dst + i) = o;
}

// ---- prep: V[bh][k][d] f32 -> vt[bh][d][k] f16 (transpose) ----
__global__ __launch_bounds__(256) void prep_vt(const float* __restrict__ V, f16* __restrict__ vt) {
  __shared__ float t[32][33];
  const int bh = blockIdx.z, k0 = blockIdx.x * 32, d0 = blockIdx.y * 32;
  const float* src = V + ((size_t)bh * KL + k0) * DKD + d0;
#pragma unroll
  for (int j = 0; j < 4; ++j) {
    int kk = threadIdx.y * 4 + j;
    t[kk][threadIdx.x] = src[kk * DKD + threadIdx.x];
  }
  __syncthreads();
  f16* dst = vt + ((size_t)bh * DKD + d0) * KL + k0;
#pragma unroll
  for (int j = 0; j < 4; ++j) {
    int dd = threadIdx.y * 4 + j;
    dst[dd * KL + threadIdx.x] = (f16)t[threadIdx.x][dd];
  }
}

// ---- stats: K-quarter staged in LDS (swizzled), 4 waves compute from LDS ----
__global__ __launch_bounds__(256) void stats_lds(const f16* __restrict__ qf,
    const f16* __restrict__ kf, float* __restrict__ prs4) {
  __shared__ __align__(16) char kb[32768];
  const int tid = threadIdx.x, lane = tid & 63, w = tid >> 6;
  const int m = lane & 15, g = lane >> 4;
  int id = blockIdx.x;
  const int b = id & 7, h = (id >> 3) & 7, kq = (id >> 6) & 3, q64 = (id >> 8) & 15;
  const int bh = b * 8 + h;

  const f16* sbase = kf + (((size_t)bh << 10) + kq * 256) * DKD;
#pragma unroll
  for (int j = 0; j < 8; ++j) {
    int idx = j * 256 + tid;
    int r = idx >> 3, c = idx & 7;
    f16x8 v = *reinterpret_cast<const f16x8*>(sbase + r * DKD + c * 8);
    *reinterpret_cast<f16x8*>(kb + r * 128 + ((c ^ (r & 7)) << 4)) = v;
  }
  const int q0 = q64 * 64 + w * 16;
  const f16* qp = qf + (((size_t)bh << 10) + q0 + m) * DKD + g * 8;
  f16x8 qv0 = *reinterpret_cast<const f16x8*>(qp);
  f16x8 qv1 = *reinterpret_cast<const f16x8*>(qp + 32);
  __syncthreads();

  float part[4] = {0.f, 0.f, 0.f, 0.f};
#pragma unroll 4
  for (int kt = 0; kt < 16; ++kt) {
    const int row = kt * 16 + m;
    f16x8 k0f = *reinterpret_cast<const f16x8*>(kb + row * 128 + ((g ^ (m & 7)) << 4));
    f16x8 k1f = *reinterpret_cast<const f16x8*>(kb + row * 128 + (((g + 4) ^ (m & 7)) << 4));
    f32x4 acc = {0.f, 0.f, 0.f, 0.f};
    acc = __builtin_amdgcn_mfma_f32_16x16x32_f16(qv0, k0f, acc, 0, 0, 0);
    acc = __builtin_amdgcn_mfma_f32_16x16x32_f16(qv1, k1f, acc, 0, 0, 0);
#pragma unroll
    for (int ri = 0; ri < 4; ++ri) part[ri] += __expf(acc[ri]);
  }
#pragma unroll
  for (int ri = 0; ri < 4; ++ri) {
    float v = part[ri];
    v += __shfl_xor(v, 1); v += __shfl_xor(v, 2);
    v += __shfl_xor(v, 4); v += __shfl_xor(v, 8);
    part[ri] = v;
  }
  if (m == 0) {
#pragma unroll
    for (int ri = 0; ri < 4; ++ri)
      prs4[((size_t)kq * 64 + bh) * QL + q0 + g * 4 + ri] = part[ri];
  }
}

// ---- lrs[bh][q] = log(sum of 4 partials) ----
__global__ __launch_bounds__(256) void stats_red(const float* __restrict__ prs4,
                                                 float* __restrict__ lrs) {
  int i = (blockIdx.x * 256 + threadIdx.x) * 4;
  float4 a = *reinterpret_cast<const float4*>(prs4 + i);
  float4 c = *reinterpret_cast<const float4*>(prs4 + 65536 + i);
  float4 d = *reinterpret_cast<const float4*>(prs4 + 131072 + i);
  float4 e = *reinterpret_cast<const float4*>(prs4 + 196608 + i);
  float4 o;
  o.x = __logf(a.x + c.x + d.x + e.x);
  o.y = __logf(a.y + c.y + d.y + e.y);
  o.z = __logf(a.z + c.z + d.z + e.z);
  o.w = __logf(a.w + c.w + d.w + e.w);
  *reinterpret_cast<float4*>(lrs + i) = o;
}

// ---- mix (single launch, full q): K-tile in LDS; S->p->mix->LN; coalesced writes ----
// grid 4096 = (b, k32, q64-tile): 16 blocks/CU queued -> backlog hides the
// per-block serial phase chain. smem: [0,32768) K tile / y bounce, [32768,40960) att.
__global__ __launch_bounds__(256) void mix_lds(const f16* __restrict__ qf,
    const f16* __restrict__ kf, const float* __restrict__ lrs_g,
    const u32* __restrict__ prm, f16* __restrict__ yq, float* __restrict__ att_map) {
  __shared__ __align__(16) char smem[40960];
  const int tid = threadIdx.x, lane = tid & 63, w = tid >> 6;
  const int m = lane & 15, g = lane >> 4;
  int id = blockIdx.x;
  const int b = id & 7, k32 = (id >> 3) & 31, q64 = (id >> 8) & 15;  // batch b -> XCD b
  const int q0 = q64 * 64 + w * 16;           // wave q base (global)
  const int k0b = k32 * 32;

  u32 prmL[80];
#pragma unroll
  for (int j = 0; j < 80; ++j) prmL[j] = prm[j];

  // stage K tile rows r = h*32+kr, swizzled
#pragma unroll
  for (int j = 0; j < 8; ++j) {
    int idx = j * 256 + tid;
    int r = idx >> 3, c = idx & 7;
    int h = r >> 5, kr = r & 31;
    const f16* src = kf + ((((size_t)(b * 8 + h)) << 10) + k0b + kr) * DKD + c * 8;
    f16x8 v = *reinterpret_cast<const f16x8*>(src);
    *reinterpret_cast<f16x8*>(smem + r * 128 + ((c ^ (r & 7)) << 4)) = v;
  }
  __syncthreads();

  const hf2 c125 = {(f16)0.125f, (f16)0.125f};
  hf2 yv[2][NH][2];   // [kt][h][q-pair]

#pragma unroll
  for (int kt = 0; kt < 2; ++kt) {
    hf2 pP[NH][2];
#pragma unroll
    for (int h = 0; h < NH; ++h) {
      const f16* qp = qf + ((((size_t)(b * 8 + h)) << 10) + q0 + m) * DKD + g * 8;
      f16x8 q0f = *reinterpret_cast<const f16x8*>(qp);
      f16x8 q1f = *reinterpret_cast<const f16x8*>(qp + 32);
      const int row = h * 32 + kt * 16 + m;
      f16x8 ka = *reinterpret_cast<const f16x8*>(smem + row * 128 + ((g ^ (m & 7)) << 4));
      f16x8 kc = *reinterpret_cast<const f16x8*>(smem + row * 128 + (((g + 4) ^ (m & 7)) << 4));
      f32x4 acc = {0.f, 0.f, 0.f, 0.f};
      acc = __builtin_amdgcn_mfma_f32_16x16x32_f16(q0f, ka, acc, 0, 0, 0);
      acc = __builtin_amdgcn_mfma_f32_16x16x32_f16(q1f, kc, acc, 0, 0, 0);
      f32x4 l4 = *reinterpret_cast<const f32x4*>(
          lrs_g + ((((size_t)(b * 8 + h)) << 10) + q0 + g * 4));
      pP[h][0] = pkrtz(__expf(acc[0] - l4[0]), __expf(acc[1] - l4[1]));
      pP[h][1] = pkrtz(__expf(acc[2] - l4[2]), __expf(acc[3] - l4[3]));
    }
    // packed head-mix + LN
    hf2 mx[NH][2];
#pragma unroll
    for (int hh = 0; hh < NH; ++hh)
#pragma unroll
      for (int pp = 0; pp < 2; ++pp) {
        hf2 acc = pP[0][pp] * bch(prmL[hh]);
#pragma unroll
        for (int j = 1; j < 8; ++j) acc += pP[j][pp] * bch(prmL[j * 8 + hh]);
        mx[hh][pp] = acc;
      }
    hf2 mu[2], var[2];
#pragma unroll
    for (int pp = 0; pp < 2; ++pp) {
      hf2 s = mx[0][pp];
#pragma unroll
      for (int hh = 1; hh < NH; ++hh) s += mx[hh][pp];
      mu[pp] = s * c125;
    }
#pragma unroll
    for (int pp = 0; pp < 2; ++pp) {
      hf2 v = {};
#pragma unroll
      for (int hh = 0; hh < NH; ++hh) {
        mx[hh][pp] -= mu[pp];
        v += mx[hh][pp] * mx[hh][pp];
      }
      var[pp] = v * c125;
    }
    hf2 rsv[2] = {pkrtz(rsqrtf((float)var[0][0] + LNEPS), rsqrtf((float)var[0][1] + LNEPS)),
                  pkrtz(rsqrtf((float)var[1][0] + LNEPS), rsqrtf((float)var[1][1] + LNEPS))};
    hf2 am[2] = {{}, {}};
#pragma unroll
    for (int hh = 0; hh < NH; ++hh)
#pragma unroll
      for (int pp = 0; pp < 2; ++pp) {
        hf2 y = mx[hh][pp] * rsv[pp] * bch(prmL[64 + hh]) + bch(prmL[72 + hh]);
        am[pp] += y;
        yv[kt][hh][pp] = y;
      }
    // att tile -> LDS (f32 region)
    const int kcol = kt * 16 + m;
#pragma unroll
    for (int pp = 0; pp < 2; ++pp) {
      int qrow0 = w * 16 + g * 4 + pp * 2;
      *reinterpret_cast<float*>(smem + 32768 + (qrow0 * 32 + kcol) * 4) = (float)am[pp][0] * 0.125f;
      *reinterpret_cast<float*>(smem + 32768 + ((qrow0 + 1) * 32 + kcol) * 4) = (float)am[pp][1] * 0.125f;
    }
  }
  __syncthreads();   // all K reads + att writes complete; K region now dead

  // y -> LDS bounce [8h][64q][32k] f16 into the dead K region
#pragma unroll
  for (int kt = 0; kt < 2; ++kt) {
    const int kcol = kt * 16 + m;
#pragma unroll
    for (int h = 0; h < NH; ++h)
#pragma unroll
      for (int pp = 0; pp < 2; ++pp) {
        int R = w * 16 + g * 4 + pp * 2;
        *reinterpret_cast<f16*>(smem + h * 4096 + R * 64 + kcol * 2) = yv[kt][h][pp][0];
        *reinterpret_cast<f16*>(smem + h * 4096 + (R + 1) * 64 + kcol * 2) = yv[kt][h][pp][1];
      }
  }
  __syncthreads();

  // coalesced write-out: y (8 x b128 per thread) + att (2 x b128 per thread)
#pragma unroll
  for (int j = 0; j < 8; ++j) {
    int idx = j * 256 + tid;
    int h = idx >> 8, R = (idx >> 2) & 63, kc = idx & 3;
    f16x8 v = *reinterpret_cast<const f16x8*>(smem + idx * 16);
    *reinterpret_cast<f16x8*>(
        yq + (((((size_t)(b * 8 + h)) << 10) + q64 * 64 + R) << 10) + k0b + kc * 8) = v;
  }
#pragma unroll
  for (int j = 0; j < 2; ++j) {
    int idx = j * 256 + tid;
    int q = idx >> 3, kc = idx & 7;
    f32x4 v = *reinterpret_cast<const f32x4*>(smem + 32768 + idx * 16);
    *reinterpret_cast<f32x4*>(
        att_map + ((((size_t)b << 10) + q64 * 64 + q) << 10) + k0b + kc * 4) = v;
  }
}

// ---- pv (single launch): wave = q16 x d32, 2 independent MFMA chains ----
// grid 2048 -> 8 blocks/CU queued; y reads L3-resident, vt reads L2-resident.
__global__ __launch_bounds__(256) void pv_kernel(const f16* __restrict__ yq,
    const f16* __restrict__ vt, float* __restrict__ outp) {
  const int tid = threadIdx.x, lane = tid & 63, w = tid >> 6;
  const int m = lane & 15, g = lane >> 4;
  int id = blockIdx.x;
  const int b = id & 7, h = (id >> 3) & 7, q64 = (id >> 6) & 15, dh = (id >> 10) & 1;
  const int bh = b * 8 + h;
  const int qloc = q64 * 64 + w * 16;

  const f16* ab = yq + ((((size_t)bh) << 10) + qloc + m) * KL + g * 8;
  const f16* vb = vt + (((size_t)bh * DKD) + dh * 32 + m) * KL + g * 8;
  f32x4 a0 = {0.f, 0.f, 0.f, 0.f}, a1 = {0.f, 0.f, 0.f, 0.f};
#pragma unroll 4
  for (int t = 0; t < 32; ++t) {
    f16x8 yf = *reinterpret_cast<const f16x8*>(ab + t * 32);
    f16x8 v0 = *reinterpret_cast<const f16x8*>(vb + t * 32);
    f16x8 v1 = *reinterpret_cast<const f16x8*>(vb + 16 * KL + t * 32);
    a0 = __builtin_amdgcn_mfma_f32_16x16x32_f16(yf, v0, a0, 0, 0, 0);
    a1 = __builtin_amdgcn_mfma_f32_16x16x32_f16(yf, v1, a1, 0, 0, 0);
  }
  const int qglob = qloc + g * 4;
  float* ob = outp + ((((size_t)bh) << 10) + qglob) * DKD + dh * 32 + m;
#pragma unroll
  for (int ri = 0; ri < 4; ++ri) {
    ob[ri * DKD] = a0[ri];
    ob[ri * DKD + 16] = a1[ri];
  }
}

extern "C" void kernel_launch(void* const* d_in, const int* in_sizes, int n_in,
                              void* d_out, int out_size, void* d_ws, size_t ws_size,
                              hipStream_t stream) {
  const float* Qm  = (const float*)d_in[0];
  const float* Km  = (const float*)d_in[1];
  const float* Vm  = (const float*)d_in[2];
  const float* hA  = (const float*)d_in[3];
  const float* lnw = (const float*)d_in[4];
  const float* lnb = (const float*)d_in[5];
  float* outp = (float*)d_out;
  float* att_map = outp + (size_t)64 * QL * DKD;

  char* ws = (char*)d_ws;
  f16* kfp    = (f16*)ws;                              // 8 MB
  f16* vtp    = (f16*)(ws + (size_t)8388608);          // 8 MB
  f16* qfp    = (f16*)(ws + (size_t)16777216);         // 8 MB
  float* prs4 = (float*)(ws + (size_t)25165824);       // 1 MB
  float* lrs  = (float*)(ws + (size_t)26214400);       // 1 MB
  u32* prm    = (u32*)(ws + (size_t)27262976);         // 320 B
  f16* yqb    = (f16*)(ws + (size_t)28311552);         // 134 MB (full y; ws is 268 MB per fill evidence)

  prep_qk<<<8192, 256, 0, stream>>>(Km, Qm, kfp, qfp, hA, lnw, lnb, prm);
  prep_vt<<<dim3(32, 2, 64), dim3(32, 8), 0, stream>>>(Vm, vtp);
  stats_lds<<<4096, 256, 0, stream>>>(qfp, kfp, prs4);
  stats_red<<<256, 256, 0, stream>>>(prs4, lrs);
  mix_lds<<<4096, 256, 0, stream>>>(qfp, kfp, lrs, prm, yqb, att_map);
  pv_kernel<<<2048, 256, 0, stream>>>(yqb, vtp, outp);
}